// Round 4
// baseline (834.767 us; speedup 1.0000x reference)
//
#include <hip/hip_runtime.h>
#include <hip/hip_fp16.h>
#include <math.h>

#define D 64
#define NPB 128          // nodes per bucket
#define NPB_SHIFT 7
#define LCAP 4096        // LDS csr capacity per bucket (expected ~2048)

// ---------------- degree histogram ----------------

__global__ void hist_kernel(const int* __restrict__ dst, int* __restrict__ deg, int e) {
    int i = blockIdx.x * blockDim.x + threadIdx.x;
    if (i < e) atomicAdd(&deg[dst[i]], 1);
}

// ---------------- exclusive scan of deg -> rs ----------------

__global__ void scan1_kernel(const int* __restrict__ deg, int* __restrict__ rs,
                             int* __restrict__ bsum, int n) {
    __shared__ int s[1024];
    int t = threadIdx.x;
    int i = blockIdx.x * 1024 + t;
    int v = (i < n) ? deg[i] : 0;
    s[t] = v;
    __syncthreads();
    for (int off = 1; off < 1024; off <<= 1) {
        int add = (t >= off) ? s[t - off] : 0;
        __syncthreads();
        s[t] += add;
        __syncthreads();
    }
    if (i < n) rs[i] = s[t] - v;
    if (t == 1023) bsum[blockIdx.x] = s[1023];
}

__global__ void scan2_kernel(int* __restrict__ bsum, int nb) {
    __shared__ int s[128];
    int t = threadIdx.x;
    int v = (t < nb) ? bsum[t] : 0;
    s[t] = v;
    __syncthreads();
    for (int off = 1; off < 128; off <<= 1) {
        int add = (t >= off) ? s[t - off] : 0;
        __syncthreads();
        s[t] += add;
        __syncthreads();
    }
    if (t < nb) bsum[t] = s[t] - v;
}

__global__ void scan3_kernel(int* __restrict__ rs, const int* __restrict__ bsum, int n) {
    int i = blockIdx.x * 1024 + threadIdx.x;
    if (i < n) rs[i] += bsum[blockIdx.x];
}

// ---------------- bucketed CSR build ----------------

__global__ void bcur_init_kernel(const int* __restrict__ rs, int* __restrict__ bcur, int nb) {
    int t = blockIdx.x * blockDim.x + threadIdx.x;
    if (t < nb) bcur[t] = rs[t << NPB_SHIFT];
}

// append (src,dst) into bucket region; writes cluster on ~782 tail lines -> L2 merges
__global__ void bin_kernel(const int* __restrict__ src, const int* __restrict__ dst,
                           int* __restrict__ bcur, int2* __restrict__ pairs, int e) {
    int i = blockIdx.x * blockDim.x + threadIdx.x;
    if (i < e) {
        int d = dst[i];
        int p = atomicAdd(&bcur[d >> NPB_SHIFT], 1);
        pairs[p] = make_int2(src[i], d);
    }
}

// one block per bucket: local CSR in LDS, then coalesced stream-out
__global__ __launch_bounds__(256) void bucket_csr_kernel(
    const int* __restrict__ rs, const int2* __restrict__ pairs,
    int* __restrict__ csr, int n, int e_total)
{
    __shared__ int lcur[NPB];
    __shared__ int lcsr[LCAP];
    const int b   = blockIdx.x;
    const int nb0 = b << NPB_SHIFT;
    const int nnode = min(NPB, n - nb0);
    const int s = rs[nb0];
    const int e = (nb0 + NPB < n) ? rs[nb0 + NPB] : e_total;
    const int cnt = e - s;
    for (int t = threadIdx.x; t < nnode; t += blockDim.x) lcur[t] = rs[nb0 + t] - s;
    __syncthreads();
    if (cnt <= LCAP) {
        for (int i = threadIdx.x; i < cnt; i += blockDim.x) {
            int2 pr = pairs[s + i];
            int p = atomicAdd(&lcur[pr.y & (NPB - 1)], 1);
            lcsr[p] = pr.x;
        }
        __syncthreads();
        for (int i = threadIdx.x; i < cnt; i += blockDim.x) csr[s + i] = lcsr[i];
    } else {  // safety fallback (statistically never for Poisson(2048))
        for (int i = threadIdx.x; i < cnt; i += blockDim.x) {
            int2 pr = pairs[s + i];
            int p = atomicAdd(&lcur[pr.y & (NPB - 1)], 1);
            csr[s + p] = pr.x;
        }
    }
}

// ---------------- fp32 -> fp16 conversion ----------------

__global__ __launch_bounds__(256) void f2h_kernel(const float* __restrict__ in,
                                                  __half* __restrict__ out, int n4) {
    int i = blockIdx.x * blockDim.x + threadIdx.x;
    if (i < n4) {
        float4 v = *(const float4*)(in + (size_t)i * 4);
        union { __half2 h[2]; float2 f; } u;
        u.h[0] = __floats2half2_rn(v.x, v.y);
        u.h[1] = __floats2half2_rn(v.z, v.w);
        *(float2*)(out + (size_t)i * 4) = u.f;
    }
}

// ---------------- SAGE layer ----------------
// One wave per node. 8 subgroups x 8 lanes; lane loads 16 B (8 halves) of its
// subgroup's edge row -> 8 rows per load instr. All ceil(deg/8) batches (<=4)
// issued via uniform branches -> up to 32 rows in flight per wave.

__device__ __forceinline__ void unpack8(float4 f, float* x) {
    __half2* h = reinterpret_cast<__half2*>(&f);
    #pragma unroll
    for (int i = 0; i < 4; ++i) {
        float2 t = __half22float2(h[i]);
        x[2 * i] = t.x; x[2 * i + 1] = t.y;
    }
}

template<int RELU>
__global__ __launch_bounds__(512) void sage_layer_kernel(
    const __half* __restrict__ in, __half* __restrict__ out,
    const float* __restrict__ W, const float* __restrict__ bias,
    const int* __restrict__ rs, const int* __restrict__ deg,
    const int* __restrict__ csr, int n)
{
    __shared__ float Wl[D * D];
    __shared__ float bl[D];
    for (int i = threadIdx.x; i < D * D; i += blockDim.x) Wl[i] = W[i];
    if (threadIdx.x < D) bl[threadIdx.x] = bias[threadIdx.x];
    __syncthreads();

    const int lane = threadIdx.x & 63;
    const int wid  = threadIdx.x >> 6;
    const int v    = blockIdx.x * (blockDim.x >> 6) + wid;
    if (v >= n) return;

    const int q   = lane & 7;    // owns dims q*8 .. q*8+7
    const int grp = lane >> 3;   // edge subgroup 0..7

    const int beg = rs[v];
    const int cnt = deg[v];
    const int end = beg + cnt;

    float acc[8];
    #pragma unroll
    for (int j = 0; j < 8; ++j) acc[j] = 0.0f;

    #define BATCH(T0)                                                          \
        {                                                                      \
            int ei = beg + (T0) + grp;                                         \
            bool ok = ei < end;                                                \
            int r = csr[ok ? ei : end - 1];                                    \
            float4 f = *(const float4*)(in + (size_t)r * D + q * 8);           \
            float x[8]; unpack8(f, x);                                         \
            float m = ok ? 1.0f : 0.0f;                                        \
            _Pragma("unroll")                                                  \
            for (int j = 0; j < 8; ++j) acc[j] = fmaf(x[j], m, acc[j]);        \
        }

    if (cnt > 0)  BATCH(0)
    if (cnt > 8)  BATCH(8)
    if (cnt > 16) BATCH(16)
    if (cnt > 24) BATCH(24)
    if (cnt > 32) {
        for (int ei = beg + 32 + grp; ei < end; ei += 8) {
            int r = csr[ei];
            float4 f = *(const float4*)(in + (size_t)r * D + q * 8);
            float x[8]; unpack8(f, x);
            #pragma unroll
            for (int j = 0; j < 8; ++j) acc[j] += x[j];
        }
    }
    #undef BATCH

    // fold 8 subgroups (lane bits 3,4,5)
    #pragma unroll
    for (int j = 0; j < 8; ++j) {
        acc[j] += __shfl_xor(acc[j], 8);
        acc[j] += __shfl_xor(acc[j], 16);
        acc[j] += __shfl_xor(acc[j], 32);
    }

    // self term + normalize
    {
        float4 sf = *(const float4*)(in + (size_t)v * D + q * 8);
        float sx[8]; unpack8(sf, sx);
        float inv = 1.0f / (float)(cnt + 1);
        #pragma unroll
        for (int j = 0; j < 8; ++j) acc[j] = (acc[j] + sx[j]) * inv;
    }

    // row-vector @ W: a[kq*8+j] lives in lane kq (elem j); lane computes out dim=lane
    float o = bl[lane];
    #pragma unroll
    for (int kq = 0; kq < 8; ++kq) {
        #pragma unroll
        for (int j = 0; j < 8; ++j) {
            float vv = __shfl(acc[j], kq);
            o = fmaf(vv, Wl[(kq * 8 + j) * D + lane], o);
        }
    }
    if (RELU) o = fmaxf(o, 0.0f);
    out[(size_t)v * D + lane] = __float2half(o);
}

// ---------------- Scoring ----------------
// 8 lanes per pair, 16 B/lane loads, unroll 2 pairs -> 4 loads in flight/lane.

__global__ __launch_bounds__(256) void score_kernel(
    const __half* __restrict__ emb,
    const int* __restrict__ a_idx, const int* __restrict__ b_idx,
    int npairs, float sign, double* __restrict__ accum)
{
    const int ll  = threadIdx.x & 7;
    const int gib = threadIdx.x >> 3;
    const int gpb = blockDim.x >> 3;
    int g = blockIdx.x * gpb + gib;
    const int stride = gridDim.x * gpb;

    float local = 0.0f;
    int p = g;
    for (; p + stride < npairs; p += 2 * stride) {
        int p2 = p + stride;
        int ai = a_idx[p],  bi = b_idx[p];
        int ci = a_idx[p2], di = b_idx[p2];
        float4 fa = *(const float4*)(emb + (size_t)ai * D + ll * 8);
        float4 fb = *(const float4*)(emb + (size_t)bi * D + ll * 8);
        float4 fc = *(const float4*)(emb + (size_t)ci * D + ll * 8);
        float4 fd = *(const float4*)(emb + (size_t)di * D + ll * 8);
        float A[8], B[8], C[8], E[8];
        unpack8(fa, A); unpack8(fb, B); unpack8(fc, C); unpack8(fd, E);
        float d0 = 0.f, d1 = 0.f;
        #pragma unroll
        for (int j = 0; j < 8; ++j) { d0 = fmaf(A[j], B[j], d0); d1 = fmaf(C[j], E[j], d1); }
        d0 += __shfl_xor(d0, 1); d1 += __shfl_xor(d1, 1);
        d0 += __shfl_xor(d0, 2); d1 += __shfl_xor(d1, 2);
        d0 += __shfl_xor(d0, 4); d1 += __shfl_xor(d1, 4);
        if (ll == 0) {
            float x0 = sign * d0, x1 = sign * d1;
            local += fmaxf(x0, 0.0f) + log1pf(expf(-fabsf(x0)));
            local += fmaxf(x1, 0.0f) + log1pf(expf(-fabsf(x1)));
        }
    }
    for (; p < npairs; p += stride) {
        int ai = a_idx[p], bi = b_idx[p];
        float4 fa = *(const float4*)(emb + (size_t)ai * D + ll * 8);
        float4 fb = *(const float4*)(emb + (size_t)bi * D + ll * 8);
        float A[8], B[8];
        unpack8(fa, A); unpack8(fb, B);
        float d = 0.f;
        #pragma unroll
        for (int j = 0; j < 8; ++j) d = fmaf(A[j], B[j], d);
        d += __shfl_xor(d, 1);
        d += __shfl_xor(d, 2);
        d += __shfl_xor(d, 4);
        if (ll == 0) {
            float x = sign * d;
            local += fmaxf(x, 0.0f) + log1pf(expf(-fabsf(x)));
        }
    }

    __shared__ float red[256];
    red[threadIdx.x] = local;
    __syncthreads();
    for (int s = blockDim.x / 2; s > 0; s >>= 1) {
        if ((int)threadIdx.x < s) red[threadIdx.x] += red[threadIdx.x + s];
        __syncthreads();
    }
    if (threadIdx.x == 0) atomicAdd(accum, (double)red[0]);
}

__global__ void finalize_kernel(const double* __restrict__ acc, float* __restrict__ out, int ep) {
    if (threadIdx.x == 0 && blockIdx.x == 0)
        out[0] = (float)(acc[0] / (double)ep);
}

// ---------------- launch ----------------

extern "C" void kernel_launch(void* const* d_in, const int* in_sizes, int n_in,
                              void* d_out, int out_size, void* d_ws, size_t ws_size,
                              hipStream_t stream) {
    const float* features = (const float*)d_in[0];
    const float* W1 = (const float*)d_in[1];
    const float* b1 = (const float*)d_in[2];
    const float* W2 = (const float*)d_in[3];
    const float* b2 = (const float*)d_in[4];
    const int* src     = (const int*)d_in[5];
    const int* dst     = (const int*)d_in[6];
    const int* pos_src = (const int*)d_in[7];
    const int* pos_dst = (const int*)d_in[8];
    const int* neg_src = (const int*)d_in[9];
    const int* neg_dst = (const int*)d_in[10];

    const int N    = in_sizes[0] / D;
    const int E    = in_sizes[5];
    const int EP   = in_sizes[7];
    const int ENEG = in_sizes[9];
    const int NB   = (N + NPB - 1) >> NPB_SHIFT;   // 782

    char* ws = (char*)d_ws;
    size_t off = 0;
    auto alloc = [&](size_t bytes) -> void* {
        void* p = ws + off;
        off += (bytes + 255) & ~(size_t)255;
        return p;
    };
    int*    deg   = (int*)alloc((size_t)N * 4);
    int*    rs    = (int*)alloc((size_t)(N + 1) * 4);
    int*    bcur  = (int*)alloc((size_t)(NB + 1) * 4);
    int*    bsum  = (int*)alloc(1024 * 4);
    int*    csr   = (int*)alloc((size_t)E * 4);
    // pairs (E*8 B) and hH (N*D*2 B) are both 12.8 MB and never live together
    size_t blk_sz = (size_t)E * 8;
    size_t hh_sz  = (size_t)N * D * 2;
    void*  blk    = alloc(blk_sz > hh_sz ? blk_sz : hh_sz);
    int2*   pairs = (int2*)blk;
    __half* hH    = (__half*)blk;
    __half* featH = (__half*)alloc((size_t)N * D * 2);
    __half* embH  = (__half*)alloc((size_t)N * D * 2);
    double* acc   = (double*)alloc(8);

    hipMemsetAsync(deg, 0, (size_t)N * 4, stream);
    hipMemsetAsync(acc, 0, 8, stream);

    const int eb  = (E + 255) / 256;
    const int nb1 = (N + 1023) / 1024;

    hist_kernel<<<eb, 256, 0, stream>>>(dst, deg, E);
    scan1_kernel<<<nb1, 1024, 0, stream>>>(deg, rs, bsum, N);
    scan2_kernel<<<1, 128, 0, stream>>>(bsum, nb1);
    scan3_kernel<<<nb1, 1024, 0, stream>>>(rs, bsum, N);
    bcur_init_kernel<<<1, 1024, 0, stream>>>(rs, bcur, NB);
    bin_kernel<<<eb, 256, 0, stream>>>(src, dst, bcur, pairs, E);
    bucket_csr_kernel<<<NB, 256, 0, stream>>>(rs, pairs, csr, N, E);

    const int n4 = (N * D) / 4;
    f2h_kernel<<<(n4 + 255) / 256, 256, 0, stream>>>(features, featH, n4);

    const int lb = (N + 7) / 8;
    sage_layer_kernel<1><<<lb, 512, 0, stream>>>(featH, hH, W1, b1, rs, deg, csr, N);
    sage_layer_kernel<0><<<lb, 512, 0, stream>>>(hH, embH, W2, b2, rs, deg, csr, N);

    int pb = (EP + 31) / 32;  if (pb > 2048) pb = 2048;
    score_kernel<<<pb, 256, 0, stream>>>(embH, pos_src, pos_dst, EP, -1.0f, acc);
    int ngb = (ENEG + 31) / 32; if (ngb > 4096) ngb = 4096;
    score_kernel<<<ngb, 256, 0, stream>>>(embH, neg_src, neg_dst, ENEG, 1.0f, acc);

    finalize_kernel<<<1, 64, 0, stream>>>(acc, (float*)d_out, EP);
}

// Round 5
// 475.914 us; speedup vs baseline: 1.7540x; 1.7540x over previous
//
#include <hip/hip_runtime.h>
#include <hip/hip_fp16.h>
#include <math.h>

#define D 64
#define NPB 64           // nodes per bucket
#define NPB_SHIFT 6
#define LCAP 2560        // LDS csr capacity per bucket (mean ~1024, sigma ~32)
#define NPART 64         // edge partitions (one workgroup each)

// ---------------- generic exclusive scan chain ----------------

__global__ void scan1_kernel(const int* __restrict__ in, int* __restrict__ out,
                             int* __restrict__ bsum, int n) {
    __shared__ int s[1024];
    int t = threadIdx.x;
    int i = blockIdx.x * 1024 + t;
    int v = (i < n) ? in[i] : 0;
    s[t] = v;
    __syncthreads();
    for (int off = 1; off < 1024; off <<= 1) {
        int add = (t >= off) ? s[t - off] : 0;
        __syncthreads();
        s[t] += add;
        __syncthreads();
    }
    if (i < n) out[i] = s[t] - v;
    if (t == 1023) bsum[blockIdx.x] = s[1023];
}

__global__ void scan2_kernel(int* __restrict__ bsum, int nb) {
    __shared__ int s[128];
    int t = threadIdx.x;
    int v = (t < nb) ? bsum[t] : 0;
    s[t] = v;
    __syncthreads();
    for (int off = 1; off < 128; off <<= 1) {
        int add = (t >= off) ? s[t - off] : 0;
        __syncthreads();
        s[t] += add;
        __syncthreads();
    }
    if (t < nb) bsum[t] = s[t] - v;
}

__global__ void scan3_kernel(int* __restrict__ out, const int* __restrict__ bsum, int n) {
    int i = blockIdx.x * 1024 + threadIdx.x;
    if (i < n) out[i] += bsum[blockIdx.x];
}

// ---------------- two-level counting sort (no global atomics) ----------------

// A: per-partition LDS histogram over buckets
__global__ __launch_bounds__(256) void part_hist_kernel(
    const int* __restrict__ dst, int* __restrict__ harr,
    int e, int nb, int chunk)
{
    extern __shared__ int sh[];
    const int p = blockIdx.x;
    for (int i = threadIdx.x; i < nb; i += 256) sh[i] = 0;
    __syncthreads();
    const int s = p * chunk, ee = min(e, s + chunk);
    for (int i = s + threadIdx.x; i < ee; i += 256)
        atomicAdd(&sh[dst[i] >> NPB_SHIFT], 1);
    __syncthreads();
    for (int b = threadIdx.x; b < nb; b += 256) harr[b * NPART + p] = sh[b];
}

// C: append pairs into private (bucket,partition) slots; LDS cursors only
__global__ __launch_bounds__(256) void part_scatter_kernel(
    const int* __restrict__ src, const int* __restrict__ dst,
    const int* __restrict__ soff, int2* __restrict__ pairs,
    int e, int nb, int chunk)
{
    extern __shared__ int cur[];
    const int p = blockIdx.x;
    for (int b = threadIdx.x; b < nb; b += 256) cur[b] = soff[b * NPART + p];
    __syncthreads();
    const int s = p * chunk, ee = min(e, s + chunk);
    for (int i = s + threadIdx.x; i < ee; i += 256) {
        int d = dst[i];
        int pos = atomicAdd(&cur[d >> NPB_SHIFT], 1);
        pairs[pos] = make_int2(src[i], d);
    }
}

// D: per-bucket — stage pairs in LDS, per-node deg/rs, place csr, coalesced out
__global__ __launch_bounds__(256) void bucket_build_kernel(
    const int* __restrict__ soff, const int2* __restrict__ pairs,
    int* __restrict__ csr, int* __restrict__ rs, int* __restrict__ deg,
    int n, int e_total, int nb)
{
    __shared__ int2 sp[LCAP];
    __shared__ int lcsr[LCAP];
    __shared__ int dcount[NPB];
    __shared__ int dexcl[NPB];
    __shared__ int cur2[NPB];
    const int b    = blockIdx.x;
    const int base = soff[b * NPART];
    const int end  = (b + 1 < nb) ? soff[(b + 1) * NPART] : e_total;
    const int cnt  = end - base;
    const int nb0  = b << NPB_SHIFT;
    const int nnode = min(NPB, n - nb0);
    const int tid  = threadIdx.x;

    if (tid < NPB) { dcount[tid] = 0; cur2[tid] = 0; }
    __syncthreads();

    if (cnt <= LCAP) {
        for (int i = tid; i < cnt; i += 256) sp[i] = pairs[base + i];
        __syncthreads();
        for (int i = tid; i < cnt; i += 256) atomicAdd(&dcount[sp[i].y & (NPB - 1)], 1);
        __syncthreads();
        if (tid == 0) {
            int run = 0;
            for (int t = 0; t < nnode; ++t) { dexcl[t] = run; run += dcount[t]; }
        }
        __syncthreads();
        if (tid < nnode) {
            deg[nb0 + tid] = dcount[tid];
            rs[nb0 + tid]  = base + dexcl[tid];
        }
        for (int i = tid; i < cnt; i += 256) {
            int2 pr = sp[i];
            int ln = pr.y & (NPB - 1);
            int pos = dexcl[ln] + atomicAdd(&cur2[ln], 1);
            lcsr[pos] = pr.x;
        }
        __syncthreads();
        for (int i = tid; i < cnt; i += 256) csr[base + i] = lcsr[i];
    } else {  // statistically unreachable fallback
        for (int i = tid; i < cnt; i += 256) atomicAdd(&dcount[pairs[base + i].y & (NPB - 1)], 1);
        __syncthreads();
        if (tid == 0) {
            int run = 0;
            for (int t = 0; t < nnode; ++t) { dexcl[t] = run; run += dcount[t]; }
        }
        __syncthreads();
        if (tid < nnode) {
            deg[nb0 + tid] = dcount[tid];
            rs[nb0 + tid]  = base + dexcl[tid];
        }
        for (int i = tid; i < cnt; i += 256) {
            int2 pr = pairs[base + i];
            int ln = pr.y & (NPB - 1);
            int pos = dexcl[ln] + atomicAdd(&cur2[ln], 1);
            csr[base + pos] = pr.x;
        }
    }
}

// ---------------- fp32 -> fp16 conversion ----------------

__global__ __launch_bounds__(256) void f2h_kernel(const float* __restrict__ in,
                                                  __half* __restrict__ out, int n4) {
    int i = blockIdx.x * blockDim.x + threadIdx.x;
    if (i < n4) {
        float4 v = *(const float4*)(in + (size_t)i * 4);
        union { __half2 h[2]; float2 f; } u;
        u.h[0] = __floats2half2_rn(v.x, v.y);
        u.h[1] = __floats2half2_rn(v.z, v.w);
        *(float2*)(out + (size_t)i * 4) = u.f;
    }
}

// ---------------- SAGE layer ----------------

__device__ __forceinline__ void unpack8(float4 f, float* x) {
    __half2* h = reinterpret_cast<__half2*>(&f);
    #pragma unroll
    for (int i = 0; i < 4; ++i) {
        float2 t = __half22float2(h[i]);
        x[2 * i] = t.x; x[2 * i + 1] = t.y;
    }
}

template<int RELU>
__global__ __launch_bounds__(512) void sage_layer_kernel(
    const __half* __restrict__ in, __half* __restrict__ out,
    const float* __restrict__ W, const float* __restrict__ bias,
    const int* __restrict__ rs, const int* __restrict__ deg,
    const int* __restrict__ csr, int n)
{
    __shared__ float Wl[D * D];
    __shared__ float bl[D];
    for (int i = threadIdx.x; i < D * D; i += blockDim.x) Wl[i] = W[i];
    if (threadIdx.x < D) bl[threadIdx.x] = bias[threadIdx.x];
    __syncthreads();

    const int lane = threadIdx.x & 63;
    const int wid  = threadIdx.x >> 6;
    const int v    = blockIdx.x * (blockDim.x >> 6) + wid;
    if (v >= n) return;

    const int q   = lane & 7;
    const int grp = lane >> 3;

    const int beg = rs[v];
    const int cnt = deg[v];
    const int end = beg + cnt;

    float acc[8];
    #pragma unroll
    for (int j = 0; j < 8; ++j) acc[j] = 0.0f;

    #define BATCH(T0)                                                          \
        {                                                                      \
            int ei = beg + (T0) + grp;                                         \
            bool ok = ei < end;                                                \
            int r = csr[ok ? ei : end - 1];                                    \
            float4 f = *(const float4*)(in + (size_t)r * D + q * 8);           \
            float x[8]; unpack8(f, x);                                         \
            float m = ok ? 1.0f : 0.0f;                                        \
            _Pragma("unroll")                                                  \
            for (int j = 0; j < 8; ++j) acc[j] = fmaf(x[j], m, acc[j]);        \
        }

    if (cnt > 0)  BATCH(0)
    if (cnt > 8)  BATCH(8)
    if (cnt > 16) BATCH(16)
    if (cnt > 24) BATCH(24)
    if (cnt > 32) {
        for (int ei = beg + 32 + grp; ei < end; ei += 8) {
            int r = csr[ei];
            float4 f = *(const float4*)(in + (size_t)r * D + q * 8);
            float x[8]; unpack8(f, x);
            #pragma unroll
            for (int j = 0; j < 8; ++j) acc[j] += x[j];
        }
    }
    #undef BATCH

    #pragma unroll
    for (int j = 0; j < 8; ++j) {
        acc[j] += __shfl_xor(acc[j], 8);
        acc[j] += __shfl_xor(acc[j], 16);
        acc[j] += __shfl_xor(acc[j], 32);
    }

    {
        float4 sf = *(const float4*)(in + (size_t)v * D + q * 8);
        float sx[8]; unpack8(sf, sx);
        float inv = 1.0f / (float)(cnt + 1);
        #pragma unroll
        for (int j = 0; j < 8; ++j) acc[j] = (acc[j] + sx[j]) * inv;
    }

    float o = bl[lane];
    #pragma unroll
    for (int kq = 0; kq < 8; ++kq) {
        #pragma unroll
        for (int j = 0; j < 8; ++j) {
            float vv = __shfl(acc[j], kq);
            o = fmaf(vv, Wl[(kq * 8 + j) * D + lane], o);
        }
    }
    if (RELU) o = fmaxf(o, 0.0f);
    out[(size_t)v * D + lane] = __float2half(o);
}

// ---------------- Scoring ----------------

__global__ __launch_bounds__(256) void score_kernel(
    const __half* __restrict__ emb,
    const int* __restrict__ a_idx, const int* __restrict__ b_idx,
    int npairs, float sign, double* __restrict__ accum)
{
    const int ll  = threadIdx.x & 7;
    const int gib = threadIdx.x >> 3;
    const int gpb = blockDim.x >> 3;
    int g = blockIdx.x * gpb + gib;
    const int stride = gridDim.x * gpb;

    float local = 0.0f;
    int p = g;
    for (; p + stride < npairs; p += 2 * stride) {
        int p2 = p + stride;
        int ai = a_idx[p],  bi = b_idx[p];
        int ci = a_idx[p2], di = b_idx[p2];
        float4 fa = *(const float4*)(emb + (size_t)ai * D + ll * 8);
        float4 fb = *(const float4*)(emb + (size_t)bi * D + ll * 8);
        float4 fc = *(const float4*)(emb + (size_t)ci * D + ll * 8);
        float4 fd = *(const float4*)(emb + (size_t)di * D + ll * 8);
        float A[8], B[8], C[8], E[8];
        unpack8(fa, A); unpack8(fb, B); unpack8(fc, C); unpack8(fd, E);
        float d0 = 0.f, d1 = 0.f;
        #pragma unroll
        for (int j = 0; j < 8; ++j) { d0 = fmaf(A[j], B[j], d0); d1 = fmaf(C[j], E[j], d1); }
        d0 += __shfl_xor(d0, 1); d1 += __shfl_xor(d1, 1);
        d0 += __shfl_xor(d0, 2); d1 += __shfl_xor(d1, 2);
        d0 += __shfl_xor(d0, 4); d1 += __shfl_xor(d1, 4);
        if (ll == 0) {
            float x0 = sign * d0, x1 = sign * d1;
            local += fmaxf(x0, 0.0f) + log1pf(expf(-fabsf(x0)));
            local += fmaxf(x1, 0.0f) + log1pf(expf(-fabsf(x1)));
        }
    }
    for (; p < npairs; p += stride) {
        int ai = a_idx[p], bi = b_idx[p];
        float4 fa = *(const float4*)(emb + (size_t)ai * D + ll * 8);
        float4 fb = *(const float4*)(emb + (size_t)bi * D + ll * 8);
        float A[8], B[8];
        unpack8(fa, A); unpack8(fb, B);
        float d = 0.f;
        #pragma unroll
        for (int j = 0; j < 8; ++j) d = fmaf(A[j], B[j], d);
        d += __shfl_xor(d, 1);
        d += __shfl_xor(d, 2);
        d += __shfl_xor(d, 4);
        if (ll == 0) {
            float x = sign * d;
            local += fmaxf(x, 0.0f) + log1pf(expf(-fabsf(x)));
        }
    }

    __shared__ float red[256];
    red[threadIdx.x] = local;
    __syncthreads();
    for (int s = blockDim.x / 2; s > 0; s >>= 1) {
        if ((int)threadIdx.x < s) red[threadIdx.x] += red[threadIdx.x + s];
        __syncthreads();
    }
    if (threadIdx.x == 0) atomicAdd(accum, (double)red[0]);
}

__global__ void finalize_kernel(const double* __restrict__ acc, float* __restrict__ out, int ep) {
    if (threadIdx.x == 0 && blockIdx.x == 0)
        out[0] = (float)(acc[0] / (double)ep);
}

// ---------------- launch ----------------

extern "C" void kernel_launch(void* const* d_in, const int* in_sizes, int n_in,
                              void* d_out, int out_size, void* d_ws, size_t ws_size,
                              hipStream_t stream) {
    const float* features = (const float*)d_in[0];
    const float* W1 = (const float*)d_in[1];
    const float* b1 = (const float*)d_in[2];
    const float* W2 = (const float*)d_in[3];
    const float* b2 = (const float*)d_in[4];
    const int* src     = (const int*)d_in[5];
    const int* dst     = (const int*)d_in[6];
    const int* pos_src = (const int*)d_in[7];
    const int* pos_dst = (const int*)d_in[8];
    const int* neg_src = (const int*)d_in[9];
    const int* neg_dst = (const int*)d_in[10];

    const int N    = in_sizes[0] / D;
    const int E    = in_sizes[5];
    const int EP   = in_sizes[7];
    const int ENEG = in_sizes[9];
    const int NB   = (N + NPB - 1) >> NPB_SHIFT;   // 1563 for N=100000

    char* ws = (char*)d_ws;
    size_t off = 0;
    auto alloc = [&](size_t bytes) -> void* {
        void* p = ws + off;
        off += (bytes + 255) & ~(size_t)255;
        return p;
    };
    int*    deg   = (int*)alloc((size_t)N * 4);
    int*    rs    = (int*)alloc((size_t)(N + 1) * 4);
    int*    harr  = (int*)alloc((size_t)NB * NPART * 4);
    int*    soff  = (int*)alloc((size_t)NB * NPART * 4);
    int*    bsum  = (int*)alloc(1024 * 4);
    int*    csr   = (int*)alloc((size_t)E * 4);
    // pairs (E*8 B) and hH (N*D*2 B) never live simultaneously
    size_t blk_sz = (size_t)E * 8;
    size_t hh_sz  = (size_t)N * D * 2;
    void*  blk    = alloc(blk_sz > hh_sz ? blk_sz : hh_sz);
    int2*   pairs = (int2*)blk;
    __half* hH    = (__half*)blk;
    __half* featH = (__half*)alloc((size_t)N * D * 2);
    __half* embH  = (__half*)alloc((size_t)N * D * 2);
    double* acc   = (double*)alloc(8);

    hipMemsetAsync(acc, 0, 8, stream);

    const int chunk = (E + NPART - 1) / NPART;
    const size_t ldsNB = (size_t)NB * 4;

    part_hist_kernel<<<NPART, 256, ldsNB, stream>>>(dst, harr, E, NB, chunk);
    const int scn = NB * NPART;                   // 100,032
    const int nbs = (scn + 1023) / 1024;          // 98 <= 128
    scan1_kernel<<<nbs, 1024, 0, stream>>>(harr, soff, bsum, scn);
    scan2_kernel<<<1, 128, 0, stream>>>(bsum, nbs);
    scan3_kernel<<<nbs, 1024, 0, stream>>>(soff, bsum, scn);
    part_scatter_kernel<<<NPART, 256, ldsNB, stream>>>(src, dst, soff, pairs, E, NB, chunk);
    bucket_build_kernel<<<NB, 256, 0, stream>>>(soff, pairs, csr, rs, deg, N, E, NB);

    const int n4 = (N * D) / 4;
    f2h_kernel<<<(n4 + 255) / 256, 256, 0, stream>>>(features, featH, n4);

    const int lb = (N + 7) / 8;
    sage_layer_kernel<1><<<lb, 512, 0, stream>>>(featH, hH, W1, b1, rs, deg, csr, N);
    sage_layer_kernel<0><<<lb, 512, 0, stream>>>(hH, embH, W2, b2, rs, deg, csr, N);

    int pb = (EP + 31) / 32;  if (pb > 2048) pb = 2048;
    score_kernel<<<pb, 256, 0, stream>>>(embH, pos_src, pos_dst, EP, -1.0f, acc);
    int ngb = (ENEG + 31) / 32; if (ngb > 4096) ngb = 4096;
    score_kernel<<<ngb, 256, 0, stream>>>(embH, neg_src, neg_dst, ENEG, 1.0f, acc);

    finalize_kernel<<<1, 64, 0, stream>>>(acc, (float*)d_out, EP);
}